// Round 1
// baseline (2208.647 us; speedup 1.0000x reference)
//
#include <hip/hip_runtime.h>
#include <math.h>

#define NPTS 32768
#define NB 32
#define PP 1024
#define KK 20

// ---------------- workspace layout ----------------
// x1   [N,64]  f32      @ 0
// idx  [N,20]  i32      @ 8388608        (idx1 then idx2)
// u1/u2 [N,128] f32     @ 11010048       (u1 uses first half)
// v1/v2 [N,128] f32     @ 27787264
// x2   [N,128] f32      @ 44564480       (also pd partials for knn2)
// h    [N,128] f32      @ 61341696       (also pi partials for knn2)
// part [32*8*128] f32   @ 78118912
constexpr size_t SZ_X1  = (size_t)NPTS * 64 * 4;
constexpr size_t SZ_IDX = (size_t)NPTS * KK * 4;
constexpr size_t SZ_UV  = (size_t)NPTS * 128 * 4;
constexpr size_t OFF_X1 = 0;
constexpr size_t OFF_IDX = OFF_X1 + SZ_X1;
constexpr size_t OFF_U = OFF_IDX + SZ_IDX;
constexpr size_t OFF_V = OFF_U + SZ_UV;
constexpr size_t OFF_X2 = OFF_V + SZ_UV;
constexpr size_t OFF_H = OFF_X2 + SZ_UV;
constexpr size_t OFF_PART = OFF_H + SZ_UV;

// ---------------- kNN ----------------
// Block = 128 threads, each thread owns one point i of one cloud; block handles
// a q-range of PP/S candidates. Top-K kept as sorted insertion list in LDS.
// S=1 writes final idx directly; S>1 writes partial (dist,idx) lists for merge.
template <int D, int S>
__global__ __launch_bounds__(128) void knn_partial(const float* __restrict__ x,
                                                   float* __restrict__ pd,
                                                   int* __restrict__ pi,
                                                   int* __restrict__ idx_out) {
  constexpr int PPB = 128;
  constexpr int NT = PP / PPB;  // 8 point-tiles per cloud
  constexpr int QR = PP / S;    // q-range per s
  int blk = blockIdx.x;
  int s = blk % S;
  int tile = (blk / S) % NT;
  int b = blk / (S * NT);
  int tid = threadIdx.x;
  int i = tile * PPB + tid;  // local point id in cloud
  const float* xb = x + (size_t)b * PP * D;

  __shared__ float xq[128 * D];
  __shared__ float kd[PPB * KK];
  __shared__ int ki[PPB * KK];

  float xi[D];
#pragma unroll
  for (int d = 0; d < D; ++d) xi[d] = xb[(size_t)i * D + d];

  float* myd = kd + tid * KK;
  int* myi = ki + tid * KK;
#pragma unroll
  for (int j = 0; j < KK; ++j) { myd[j] = __builtin_inff(); myi[j] = 0x7fffffff; }
  float worst = __builtin_inff();

  for (int q0 = s * QR; q0 < (s + 1) * QR; q0 += 128) {
    __syncthreads();
    // cooperative vectorized stage of the q-tile
    const float4* src = (const float4*)(xb + (size_t)q0 * D);
    for (int t = tid; t < 128 * D / 4; t += PPB) ((float4*)xq)[t] = src[t];
    __syncthreads();
    for (int qq = 0; qq < 128; ++qq) {
      float dist = 0.f;
#pragma unroll
      for (int d = 0; d < D; ++d) {
        float df = xi[d] - xq[qq * D + d];
        dist = fmaf(df, df, dist);
      }
      if (dist < worst) {
        int q = q0 + qq;
        int j = KK - 1;
        while (j > 0 && myd[j - 1] > dist) {
          myd[j] = myd[j - 1];
          myi[j] = myi[j - 1];
          --j;
        }
        myd[j] = dist;
        myi[j] = q;
        worst = myd[KK - 1];
      }
    }
  }
  size_t base = (size_t)b * PP + i;
  if constexpr (S == 1) {
#pragma unroll
    for (int j = 0; j < KK; ++j) idx_out[base * KK + j] = myi[j];
  } else {
#pragma unroll
    for (int j = 0; j < KK; ++j) {
      pd[(base * S + s) * KK + j] = myd[j];
      pi[(base * S + s) * KK + j] = myi[j];
    }
  }
}

template <int S>
__global__ __launch_bounds__(256) void knn_merge(const float* __restrict__ pd,
                                                 const int* __restrict__ pi,
                                                 int* __restrict__ idx_out) {
  int gid = blockIdx.x * 256 + threadIdx.x;  // global point id
  __shared__ float kd[256 * KK];
  __shared__ int ki[256 * KK];
  float* myd = kd + threadIdx.x * KK;
  int* myi = ki + threadIdx.x * KK;
#pragma unroll
  for (int j = 0; j < KK; ++j) { myd[j] = __builtin_inff(); myi[j] = 0x7fffffff; }
  float worst = __builtin_inff();
  int worsti = 0x7fffffff;
  for (int s = 0; s < S; ++s) {
    const float* gd = pd + ((size_t)gid * S + s) * KK;
    const int* gi = pi + ((size_t)gid * S + s) * KK;
    for (int j = 0; j < KK; ++j) {
      float d = gd[j];
      int q = gi[j];
      if (d < worst || (d == worst && q < worsti)) {
        int t = KK - 1;
        while (t > 0 && (myd[t - 1] > d || (myd[t - 1] == d && myi[t - 1] > q))) {
          myd[t] = myd[t - 1];
          myi[t] = myi[t - 1];
          --t;
        }
        myd[t] = d;
        myi[t] = q;
        worst = myd[KK - 1];
        worsti = myi[KK - 1];
      } else {
        break;  // each s-group sorted ascending by (d,q): rest can't qualify
      }
    }
  }
#pragma unroll
  for (int j = 0; j < KK; ++j) idx_out[(size_t)gid * KK + j] = myi[j];
}

// ---------------- EdgeConv1 ----------------
// u1[i][c] = b1[c] + pos_i @ (W1_top - W1_bot)[.,c];  v1[j][c] = pos_j @ W1_bot[.,c]
__global__ __launch_bounds__(256) void precompute1(const float* __restrict__ pos,
                                                   const float* __restrict__ W1,
                                                   const float* __restrict__ b1,
                                                   float* __restrict__ u1,
                                                   float* __restrict__ v1) {
  int gid = blockIdx.x * 256 + threadIdx.x;  // over N*64
  int i = gid >> 6, c = gid & 63;
  float p0 = pos[(size_t)i * 3 + 0], p1 = pos[(size_t)i * 3 + 1], p2 = pos[(size_t)i * 3 + 2];
  float a0 = W1[0 * 64 + c], a1 = W1[1 * 64 + c], a2 = W1[2 * 64 + c];
  float g0 = W1[3 * 64 + c], g1 = W1[4 * 64 + c], g2 = W1[5 * 64 + c];
  float v = fmaf(p0, g0, fmaf(p1, g1, p2 * g2));
  float u = b1[c];
  u = fmaf(p0, a0 - g0, u);
  u = fmaf(p1, a1 - g1, u);
  u = fmaf(p2, a2 - g2, u);
  u1[gid] = u;
  v1[gid] = v;
}

// wave per point; lane = channel. hidden_l = relu((u1+v1)*scale+bias) per lane,
// then cross-lane 64x64 GEMM with W2 staged in LDS; max over K edges.
__global__ __launch_bounds__(256) void edge_conv1(const float* __restrict__ u1,
                                                  const float* __restrict__ v1,
                                                  const int* __restrict__ idx,
                                                  const float* __restrict__ W2,
                                                  const float* __restrict__ scale,
                                                  const float* __restrict__ bias,
                                                  const float* __restrict__ b2,
                                                  float* __restrict__ x1) {
  __shared__ float W2s[64 * 64];
  for (int t = threadIdx.x; t < 64 * 64; t += 256) W2s[t] = W2[t];
  __syncthreads();
  int wave = threadIdx.x >> 6, lane = threadIdx.x & 63;
  int i = blockIdx.x * 4 + wave;
  int b = i >> 10;
  float uc = u1[(size_t)i * 64 + lane];
  float sc = scale[lane], bi = bias[lane];
  float accmax = -__builtin_inff();
  const int* myidx = idx + (size_t)i * KK;
  for (int k = 0; k < KK; ++k) {
    int j = (b << 10) + myidx[k];
    float vv = v1[(size_t)j * 64 + lane];
    float h = fmaf(uc + vv, sc, bi);
    h = fmaxf(h, 0.f);
    float out = 0.f;
#pragma unroll
    for (int t = 0; t < 64; ++t) {
      float hv = __shfl(h, t, 64);
      out = fmaf(hv, W2s[t * 64 + lane], out);
    }
    accmax = fmaxf(accmax, out);
  }
  x1[(size_t)i * 64 + lane] = accmax + b2[lane];
}

// ---------------- EdgeConv2 (linear -> u/v split) ----------------
__global__ __launch_bounds__(256) void precompute2(const float* __restrict__ x1,
                                                   const float* __restrict__ W,
                                                   const float* __restrict__ bb,
                                                   float* __restrict__ u2,
                                                   float* __restrict__ v2) {
  int gid = blockIdx.x * 256 + threadIdx.x;  // over (N/4)*128
  int c = gid & 127;
  int i0 = (gid >> 7) * 4;
  const float* a = x1 + (size_t)i0 * 64;
  float u0, u1r, u2r, u3, v0, v1r, v2r, v3;
  u0 = u1r = u2r = u3 = bb[c];
  v0 = v1r = v2r = v3 = 0.f;
  for (int t = 0; t < 64; ++t) {
    float wa = W[t * 128 + c];
    float wb = W[(64 + t) * 128 + c];
    float wd = wa - wb;
    float e0 = a[t], e1 = a[64 + t], e2 = a[128 + t], e3 = a[192 + t];
    u0 = fmaf(e0, wd, u0); v0 = fmaf(e0, wb, v0);
    u1r = fmaf(e1, wd, u1r); v1r = fmaf(e1, wb, v1r);
    u2r = fmaf(e2, wd, u2r); v2r = fmaf(e2, wb, v2r);
    u3 = fmaf(e3, wd, u3); v3 = fmaf(e3, wb, v3);
  }
  u2[(size_t)i0 * 128 + c] = u0;
  u2[(size_t)(i0 + 1) * 128 + c] = u1r;
  u2[(size_t)(i0 + 2) * 128 + c] = u2r;
  u2[(size_t)(i0 + 3) * 128 + c] = u3;
  v2[(size_t)i0 * 128 + c] = v0;
  v2[(size_t)(i0 + 1) * 128 + c] = v1r;
  v2[(size_t)(i0 + 2) * 128 + c] = v2r;
  v2[(size_t)(i0 + 3) * 128 + c] = v3;
}

__global__ __launch_bounds__(256) void gathermax2(const float* __restrict__ u2,
                                                  const float* __restrict__ v2,
                                                  const int* __restrict__ idx,
                                                  float* __restrict__ x2) {
  int gid = blockIdx.x * 256 + threadIdx.x;  // over N*128
  int i = gid >> 7, c = gid & 127;
  int b = i >> 10;
  const int* myidx = idx + (size_t)i * KK;
  float m = -__builtin_inff();
  for (int k = 0; k < KK; ++k) {
    int j = (b << 10) + myidx[k];
    m = fmaxf(m, v2[(size_t)j * 128 + c]);
  }
  x2[gid] = u2[gid] + m;
}

// ---------------- final linear + segment max ----------------
__global__ __launch_bounds__(256) void lin_kernel(const float* __restrict__ x1,
                                                  const float* __restrict__ x2,
                                                  const float* __restrict__ LW,
                                                  const float* __restrict__ lb,
                                                  float* __restrict__ h) {
  int gid = blockIdx.x * 256 + threadIdx.x;  // over (N/4)*128
  int c = gid & 127;
  int i0 = (gid >> 7) * 4;
  float o0 = lb[c], o1 = o0, o2 = o0, o3 = o0;
  const float* a = x1 + (size_t)i0 * 64;
  for (int t = 0; t < 64; ++t) {
    float w = LW[t * 128 + c];
    o0 = fmaf(a[t], w, o0);
    o1 = fmaf(a[64 + t], w, o1);
    o2 = fmaf(a[128 + t], w, o2);
    o3 = fmaf(a[192 + t], w, o3);
  }
  const float* g = x2 + (size_t)i0 * 128;
  for (int t = 0; t < 128; ++t) {
    float w = LW[(64 + t) * 128 + c];
    o0 = fmaf(g[t], w, o0);
    o1 = fmaf(g[128 + t], w, o1);
    o2 = fmaf(g[256 + t], w, o2);
    o3 = fmaf(g[384 + t], w, o3);
  }
  h[(size_t)i0 * 128 + c] = o0;
  h[(size_t)(i0 + 1) * 128 + c] = o1;
  h[(size_t)(i0 + 2) * 128 + c] = o2;
  h[(size_t)(i0 + 3) * 128 + c] = o3;
}

__global__ __launch_bounds__(128) void segmax_a(const float* __restrict__ h,
                                                float* __restrict__ part) {
  int b = blockIdx.x >> 3, chunk = blockIdx.x & 7;
  int c = threadIdx.x;
  float m = -__builtin_inff();
  for (int p = 0; p < 128; ++p) {
    size_t i = (size_t)b * PP + chunk * 128 + p;
    m = fmaxf(m, h[i * 128 + c]);
  }
  part[(size_t)blockIdx.x * 128 + c] = m;
}

__global__ __launch_bounds__(128) void segmax_b(const float* __restrict__ part,
                                                float* __restrict__ out) {
  int b = blockIdx.x;
  int c = threadIdx.x;
  float m = -__builtin_inff();
  for (int k = 0; k < 8; ++k) m = fmaxf(m, part[((size_t)b * 8 + k) * 128 + c]);
  out[(size_t)b * 128 + c] = m;
}

// ---------------- launch ----------------
extern "C" void kernel_launch(void* const* d_in, const int* in_sizes, int n_in,
                              void* d_out, int out_size, void* d_ws, size_t ws_size,
                              hipStream_t stream) {
  const float* pos = (const float*)d_in[0];
  const float* W1 = (const float*)d_in[2];
  const float* b1 = (const float*)d_in[3];
  const float* bn_s = (const float*)d_in[4];
  const float* bn_b = (const float*)d_in[5];
  const float* W2 = (const float*)d_in[6];
  const float* b2 = (const float*)d_in[7];
  const float* cW = (const float*)d_in[8];
  const float* cb = (const float*)d_in[9];
  const float* LW = (const float*)d_in[10];
  const float* lb = (const float*)d_in[11];
  float* out = (float*)d_out;

  char* ws = (char*)d_ws;
  float* x1 = (float*)(ws + OFF_X1);
  int* idx = (int*)(ws + OFF_IDX);
  float* u1 = (float*)(ws + OFF_U);
  float* v1 = (float*)(ws + OFF_V);
  float* u2 = u1;
  float* v2 = v1;
  float* x2 = (float*)(ws + OFF_X2);
  float* hbuf = (float*)(ws + OFF_H);
  float* part = (float*)(ws + OFF_PART);
  float* pd = x2;       // knn2 partial dists (alias, lifetime-disjoint)
  int* pi = (int*)hbuf; // knn2 partial indices

  // 1. kNN on pos (3-dim), direct
  knn_partial<3, 1><<<NB * 8, 128, 0, stream>>>(pos, nullptr, nullptr, idx);
  // 2. u1/v1
  precompute1<<<NPTS * 64 / 256, 256, 0, stream>>>(pos, W1, b1, u1, v1);
  // 3. EdgeConv1 -> x1
  edge_conv1<<<NPTS / 4, 256, 0, stream>>>(u1, v1, idx, W2, bn_s, bn_b, b2, x1);
  // 4. kNN on x1 (64-dim), 4-way split + merge
  knn_partial<64, 4><<<NB * 8 * 4, 128, 0, stream>>>(x1, pd, pi, nullptr);
  knn_merge<4><<<NPTS / 256, 256, 0, stream>>>(pd, pi, idx);
  // 5. u2/v2
  precompute2<<<(NPTS / 4) * 128 / 256, 256, 0, stream>>>(x1, cW, cb, u2, v2);
  // 6. gather + max -> x2
  gathermax2<<<NPTS * 128 / 256, 256, 0, stream>>>(u2, v2, idx, x2);
  // 7. final linear -> h
  lin_kernel<<<(NPTS / 4) * 128 / 256, 256, 0, stream>>>(x1, x2, LW, lb, hbuf);
  // 8. segment max -> out
  segmax_a<<<NB * 8, 128, 0, stream>>>(hbuf, part);
  segmax_b<<<NB, 128, 0, stream>>>(part, out);
}

// Round 2
// 916.170 us; speedup vs baseline: 2.4107x; 2.4107x over previous
//
#include <hip/hip_runtime.h>
#include <math.h>

#define NPTS 32768
#define NB 32
#define PP 1024
#define KK 20

// ---------------- workspace layout ----------------
constexpr size_t OFF_X1 = 0;                                  // [N,64] f32
constexpr size_t OFF_IDX = OFF_X1 + (size_t)NPTS * 64 * 4;    // [N,20] i32
constexpr size_t OFF_U = OFF_IDX + (size_t)NPTS * KK * 4;     // [N,128] f32 (u1 uses 64)
constexpr size_t OFF_V = OFF_U + (size_t)NPTS * 128 * 4;      // [N,128] f32
constexpr size_t OFF_X2 = OFF_V + (size_t)NPTS * 128 * 4;     // [N,128] f32
constexpr size_t OFF_H = OFF_X2 + (size_t)NPTS * 128 * 4;     // [N,128] f32
constexpr size_t OFF_PART = OFF_H + (size_t)NPTS * 128 * 4;   // 32*8*128 f32
constexpr size_t OFF_SQN = OFF_PART + (size_t)32 * 8 * 128 * 4;  // [N] f32
// pk (partial keys, max N*8*20 u32 = 21 MB) aliases X2..H region (33.5 MB),
// lifetime-disjoint: pk is dead before x2/h are written.

// ---------------- branch-free register top-K ----------------
// l[0..19] sorted ascending (uint keys). Insert = replace worst with min,
// then one bubble pass restores sortedness. No branches, no LDS.
__device__ __forceinline__ void topk_insert(unsigned (&l)[KK], unsigned key) {
  l[KK - 1] = (key < l[KK - 1]) ? key : l[KK - 1];
#pragma unroll
  for (int j = KK - 1; j >= 1; --j) {
    unsigned a = l[j - 1], b = l[j];
    l[j - 1] = (a < b) ? a : b;
    l[j] = (a < b) ? b : a;
  }
}

// key = (dist_bits & ~0x3FF) | q : dist>=0 so uint order == float order;
// low 10 bits embed candidate idx (also gives lowest-idx tie-break like top_k).
__device__ __forceinline__ unsigned pack_key(float dist, int q) {
  return (__float_as_uint(dist) & 0xFFFFFC00u) | (unsigned)q;
}

// ---------------- kNN: register top-K, candidate-split ----------------
// 256 threads = 256 points (one point-tile); block scans candidate chunk s.
// Candidate addresses are block-uniform -> scalar loads, zero LDS.
template <int D, int S>
__global__ __launch_bounds__(256) void knn_topk(const float* __restrict__ x,
                                                const float* __restrict__ sqn,
                                                unsigned* __restrict__ pk) {
  constexpr int CH = PP / S;
  int bx = blockIdx.x;
  int s = bx % S;
  int tile = (bx / S) % (PP / 256);
  int b = bx / (S * (PP / 256));
  int i = tile * 256 + threadIdx.x;  // local point id
  const float* xb = x + (size_t)b * PP * D;

  unsigned l[KK];
#pragma unroll
  for (int j = 0; j < KK; ++j) l[j] = 0xFFFFFFFFu;

  if constexpr (D == 3) {
    float xi0 = xb[(size_t)i * 3 + 0];
    float xi1 = xb[(size_t)i * 3 + 1];
    float xi2 = xb[(size_t)i * 3 + 2];
    for (int c = 0; c < CH; ++c) {
      int q = s * CH + c;  // block-uniform
      const float* cp = xb + (size_t)q * 3;
      float d0 = xi0 - cp[0], d1 = xi1 - cp[1], d2 = xi2 - cp[2];
      float dist = fmaf(d0, d0, fmaf(d1, d1, d2 * d2));
      topk_insert(l, pack_key(dist, q));
    }
  } else {
    float xi[D];
    const float4* xr = (const float4*)(xb + (size_t)i * D);
#pragma unroll
    for (int t = 0; t < D / 4; ++t) {
      float4 v = xr[t];
      xi[4 * t + 0] = v.x; xi[4 * t + 1] = v.y;
      xi[4 * t + 2] = v.z; xi[4 * t + 3] = v.w;
    }
    float sqi = sqn[(size_t)b * PP + i];
    const float* sq = sqn + (size_t)b * PP;
    for (int c = 0; c < CH; ++c) {
      int q = s * CH + c;  // block-uniform
      const float4* cp = (const float4*)(xb + (size_t)q * D);
      float a0 = 0.f, a1 = 0.f, a2 = 0.f, a3 = 0.f;
#pragma unroll
      for (int t = 0; t < D / 4; ++t) {
        float4 v = cp[t];
        a0 = fmaf(xi[4 * t + 0], v.x, a0);
        a1 = fmaf(xi[4 * t + 1], v.y, a1);
        a2 = fmaf(xi[4 * t + 2], v.z, a2);
        a3 = fmaf(xi[4 * t + 3], v.w, a3);
      }
      float dot = (a0 + a1) + (a2 + a3);
      float dist = fmaf(-2.f, dot, sqi + sq[q]);
      dist = fmaxf(dist, 0.f);  // keep sign bit clear for uint ordering
      topk_insert(l, pack_key(dist, q));
    }
  }
  size_t base = ((size_t)b * PP + i) * S + s;
#pragma unroll
  for (int j = 0; j < KK; ++j) pk[base * KK + j] = l[j];
}

template <int S>
__global__ __launch_bounds__(256) void knn_merge(const unsigned* __restrict__ pk,
                                                 int* __restrict__ idx_out) {
  int p = blockIdx.x * 256 + threadIdx.x;  // global point id
  const unsigned* g = pk + (size_t)p * S * KK;
  unsigned l[KK];
#pragma unroll
  for (int j = 0; j < KK; ++j) l[j] = g[j];
  for (int s = 1; s < S; ++s) {
    const unsigned* gs = g + s * KK;
#pragma unroll
    for (int j = 0; j < KK; ++j) topk_insert(l, gs[j]);
  }
#pragma unroll
  for (int j = 0; j < KK; ++j) idx_out[(size_t)p * KK + j] = (int)(l[j] & 1023u);
}

// ---------------- EdgeConv1 ----------------
__global__ __launch_bounds__(256) void precompute1(const float* __restrict__ pos,
                                                   const float* __restrict__ W1,
                                                   const float* __restrict__ b1,
                                                   float* __restrict__ u1,
                                                   float* __restrict__ v1) {
  int gid = blockIdx.x * 256 + threadIdx.x;  // over N*64
  int i = gid >> 6, c = gid & 63;
  float p0 = pos[(size_t)i * 3 + 0], p1 = pos[(size_t)i * 3 + 1], p2 = pos[(size_t)i * 3 + 2];
  float a0 = W1[0 * 64 + c], a1 = W1[1 * 64 + c], a2 = W1[2 * 64 + c];
  float g0 = W1[3 * 64 + c], g1 = W1[4 * 64 + c], g2 = W1[5 * 64 + c];
  float v = fmaf(p0, g0, fmaf(p1, g1, p2 * g2));
  float u = b1[c];
  u = fmaf(p0, a0 - g0, u);
  u = fmaf(p1, a1 - g1, u);
  u = fmaf(p2, a2 - g2, u);
  u1[gid] = u;
  v1[gid] = v;
}

// wave per point; lane = channel. W2 column hoisted to 64 VGPRs; also emits
// sqn[i] = |x1_i|^2 for knn2 (butterfly reduce in epilogue).
__global__ __launch_bounds__(256) void edge_conv1(const float* __restrict__ u1,
                                                  const float* __restrict__ v1,
                                                  const int* __restrict__ idx,
                                                  const float* __restrict__ W2,
                                                  const float* __restrict__ scale,
                                                  const float* __restrict__ bias,
                                                  const float* __restrict__ b2,
                                                  float* __restrict__ x1,
                                                  float* __restrict__ sqn) {
  __shared__ float W2s[64 * 64];
  for (int t = threadIdx.x; t < 64 * 64; t += 256) W2s[t] = W2[t];
  __syncthreads();
  int wave = threadIdx.x >> 6, lane = threadIdx.x & 63;
  int i = blockIdx.x * 4 + wave;
  int b = i >> 10;
  float uc = u1[(size_t)i * 64 + lane];
  float sc = scale[lane], bi = bias[lane];
  float w[64];
#pragma unroll
  for (int t = 0; t < 64; ++t) w[t] = W2s[t * 64 + lane];
  float accmax = -__builtin_inff();
  const int* myidx = idx + (size_t)i * KK;
  for (int k = 0; k < KK; ++k) {
    int j = (b << 10) + myidx[k];
    float vv = v1[(size_t)j * 64 + lane];
    float h = fmaf(uc + vv, sc, bi);
    h = fmaxf(h, 0.f);
    float oa = 0.f, ob = 0.f;
#pragma unroll
    for (int t = 0; t < 64; t += 2) {
      float h0 = __shfl(h, t, 64);
      float h1 = __shfl(h, t + 1, 64);
      oa = fmaf(h0, w[t], oa);
      ob = fmaf(h1, w[t + 1], ob);
    }
    accmax = fmaxf(accmax, oa + ob);
  }
  float m = accmax + b2[lane];
  x1[(size_t)i * 64 + lane] = m;
  float ss = m * m;
#pragma unroll
  for (int o = 32; o > 0; o >>= 1) ss += __shfl_xor(ss, o, 64);
  if (lane == 0) sqn[i] = ss;
}

// ---------------- EdgeConv2 (linear -> u/v split) ----------------
__global__ __launch_bounds__(256) void precompute2(const float* __restrict__ x1,
                                                   const float* __restrict__ W,
                                                   const float* __restrict__ bb,
                                                   float* __restrict__ u2,
                                                   float* __restrict__ v2) {
  int gid = blockIdx.x * 256 + threadIdx.x;  // over (N/4)*128
  int c = gid & 127;
  int i0 = (gid >> 7) * 4;
  const float* a = x1 + (size_t)i0 * 64;
  float u0, u1r, u2r, u3, v0, v1r, v2r, v3;
  u0 = u1r = u2r = u3 = bb[c];
  v0 = v1r = v2r = v3 = 0.f;
  for (int t = 0; t < 64; ++t) {
    float wa = W[t * 128 + c];
    float wb = W[(64 + t) * 128 + c];
    float wd = wa - wb;
    float e0 = a[t], e1 = a[64 + t], e2 = a[128 + t], e3 = a[192 + t];
    u0 = fmaf(e0, wd, u0); v0 = fmaf(e0, wb, v0);
    u1r = fmaf(e1, wd, u1r); v1r = fmaf(e1, wb, v1r);
    u2r = fmaf(e2, wd, u2r); v2r = fmaf(e2, wb, v2r);
    u3 = fmaf(e3, wd, u3); v3 = fmaf(e3, wb, v3);
  }
  u2[(size_t)i0 * 128 + c] = u0;
  u2[(size_t)(i0 + 1) * 128 + c] = u1r;
  u2[(size_t)(i0 + 2) * 128 + c] = u2r;
  u2[(size_t)(i0 + 3) * 128 + c] = u3;
  v2[(size_t)i0 * 128 + c] = v0;
  v2[(size_t)(i0 + 1) * 128 + c] = v1r;
  v2[(size_t)(i0 + 2) * 128 + c] = v2r;
  v2[(size_t)(i0 + 3) * 128 + c] = v3;
}

__global__ __launch_bounds__(256) void gathermax2(const float* __restrict__ u2,
                                                  const float* __restrict__ v2,
                                                  const int* __restrict__ idx,
                                                  float* __restrict__ x2) {
  int gid = blockIdx.x * 256 + threadIdx.x;  // over N*128
  int i = gid >> 7, c = gid & 127;
  int b = i >> 10;
  const int* myidx = idx + (size_t)i * KK;
  float m = -__builtin_inff();
  for (int k = 0; k < KK; ++k) {
    int j = (b << 10) + myidx[k];
    m = fmaxf(m, v2[(size_t)j * 128 + c]);
  }
  x2[gid] = u2[gid] + m;
}

// ---------------- final linear + segment max ----------------
__global__ __launch_bounds__(256) void lin_kernel(const float* __restrict__ x1,
                                                  const float* __restrict__ x2,
                                                  const float* __restrict__ LW,
                                                  const float* __restrict__ lb,
                                                  float* __restrict__ h) {
  int gid = blockIdx.x * 256 + threadIdx.x;  // over (N/4)*128
  int c = gid & 127;
  int i0 = (gid >> 7) * 4;
  float o0 = lb[c], o1 = o0, o2 = o0, o3 = o0;
  const float* a = x1 + (size_t)i0 * 64;
  for (int t = 0; t < 64; ++t) {
    float w = LW[t * 128 + c];
    o0 = fmaf(a[t], w, o0);
    o1 = fmaf(a[64 + t], w, o1);
    o2 = fmaf(a[128 + t], w, o2);
    o3 = fmaf(a[192 + t], w, o3);
  }
  const float* g = x2 + (size_t)i0 * 128;
  for (int t = 0; t < 128; ++t) {
    float w = LW[(64 + t) * 128 + c];
    o0 = fmaf(g[t], w, o0);
    o1 = fmaf(g[128 + t], w, o1);
    o2 = fmaf(g[256 + t], w, o2);
    o3 = fmaf(g[384 + t], w, o3);
  }
  h[(size_t)i0 * 128 + c] = o0;
  h[(size_t)(i0 + 1) * 128 + c] = o1;
  h[(size_t)(i0 + 2) * 128 + c] = o2;
  h[(size_t)(i0 + 3) * 128 + c] = o3;
}

__global__ __launch_bounds__(128) void segmax_a(const float* __restrict__ h,
                                                float* __restrict__ part) {
  int b = blockIdx.x >> 3, chunk = blockIdx.x & 7;
  int c = threadIdx.x;
  float m = -__builtin_inff();
  for (int p = 0; p < 128; ++p) {
    size_t i = (size_t)b * PP + chunk * 128 + p;
    m = fmaxf(m, h[i * 128 + c]);
  }
  part[(size_t)blockIdx.x * 128 + c] = m;
}

__global__ __launch_bounds__(128) void segmax_b(const float* __restrict__ part,
                                                float* __restrict__ out) {
  int b = blockIdx.x;
  int c = threadIdx.x;
  float m = -__builtin_inff();
  for (int k = 0; k < 8; ++k) m = fmaxf(m, part[((size_t)b * 8 + k) * 128 + c]);
  out[(size_t)b * 128 + c] = m;
}

// ---------------- launch ----------------
extern "C" void kernel_launch(void* const* d_in, const int* in_sizes, int n_in,
                              void* d_out, int out_size, void* d_ws, size_t ws_size,
                              hipStream_t stream) {
  const float* pos = (const float*)d_in[0];
  const float* W1 = (const float*)d_in[2];
  const float* b1 = (const float*)d_in[3];
  const float* bn_s = (const float*)d_in[4];
  const float* bn_b = (const float*)d_in[5];
  const float* W2 = (const float*)d_in[6];
  const float* b2 = (const float*)d_in[7];
  const float* cW = (const float*)d_in[8];
  const float* cb = (const float*)d_in[9];
  const float* LW = (const float*)d_in[10];
  const float* lb = (const float*)d_in[11];
  float* out = (float*)d_out;

  char* ws = (char*)d_ws;
  float* x1 = (float*)(ws + OFF_X1);
  int* idx = (int*)(ws + OFF_IDX);
  float* u1 = (float*)(ws + OFF_U);
  float* v1 = (float*)(ws + OFF_V);
  float* u2 = u1;
  float* v2 = v1;
  float* x2 = (float*)(ws + OFF_X2);
  float* hbuf = (float*)(ws + OFF_H);
  float* part = (float*)(ws + OFF_PART);
  float* sqn = (float*)(ws + OFF_SQN);
  unsigned* pk = (unsigned*)(ws + OFF_X2);  // aliases x2..h, lifetime-disjoint

  // 1. kNN on pos (3-dim): register top-K, 4-way candidate split
  knn_topk<3, 4><<<NB * 4 * 4, 256, 0, stream>>>(pos, nullptr, pk);
  knn_merge<4><<<NPTS / 256, 256, 0, stream>>>(pk, idx);
  // 2. u1/v1
  precompute1<<<NPTS * 64 / 256, 256, 0, stream>>>(pos, W1, b1, u1, v1);
  // 3. EdgeConv1 -> x1 (+ sqn for knn2)
  edge_conv1<<<NPTS / 4, 256, 0, stream>>>(u1, v1, idx, W2, bn_s, bn_b, b2, x1, sqn);
  // 4. kNN on x1 (64-dim): register top-K, 8-way split
  knn_topk<64, 8><<<NB * 4 * 8, 256, 0, stream>>>(x1, sqn, pk);
  knn_merge<8><<<NPTS / 256, 256, 0, stream>>>(pk, idx);
  // 5. u2/v2
  precompute2<<<(NPTS / 4) * 128 / 256, 256, 0, stream>>>(x1, cW, cb, u2, v2);
  // 6. gather + max -> x2
  gathermax2<<<NPTS * 128 / 256, 256, 0, stream>>>(u2, v2, idx, x2);
  // 7. final linear -> h
  lin_kernel<<<(NPTS / 4) * 128 / 256, 256, 0, stream>>>(x1, x2, LW, lb, hbuf);
  // 8. segment max -> out
  segmax_a<<<NB * 8, 128, 0, stream>>>(hbuf, part);
  segmax_b<<<NB, 128, 0, stream>>>(part, out);
}

// Round 3
// 487.863 us; speedup vs baseline: 4.5272x; 1.8779x over previous
//
#include <hip/hip_runtime.h>
#include <math.h>

#define NPTS 32768
#define NB 32
#define PP 1024
#define KK 20

using bf16x8 = __attribute__((ext_vector_type(8))) short;
using f32x4 = __attribute__((ext_vector_type(4))) float;

// ---------------- workspace layout ----------------
constexpr size_t OFF_X1 = 0;                                  // [N,64] f32
constexpr size_t OFF_IDX = OFF_X1 + (size_t)NPTS * 64 * 4;    // [N,20] i32
constexpr size_t OFF_U = OFF_IDX + (size_t)NPTS * KK * 4;     // [N,128] f32 region
constexpr size_t OFF_V = OFF_U + (size_t)NPTS * 128 * 4;      // [N,128] f32 region
constexpr size_t OFF_X2 = OFF_V + (size_t)NPTS * 128 * 4;     // [N,128] f32
constexpr size_t OFF_H = OFF_X2 + (size_t)NPTS * 128 * 4;     // [N,128] f32
constexpr size_t OFF_PART = OFF_H + (size_t)NPTS * 128 * 4;   // 32*8*128 f32
constexpr size_t OFF_SQN = OFF_PART + (size_t)32 * 8 * 128 * 4;  // [N] f32
// x1h lives in the unused second half of the U region; x1l in second half of V
// region (both dead before precompute2 overwrites them with u2/v2).
// pk (N*8*20 u32 = 21 MB) spans X2 + start of H; dead before x2/h are written.

// ---------------- branch-free register top-K ----------------
__device__ __forceinline__ void topk_insert(unsigned (&l)[KK], unsigned key) {
  l[KK - 1] = (key < l[KK - 1]) ? key : l[KK - 1];
#pragma unroll
  for (int j = KK - 1; j >= 1; --j) {
    unsigned a = l[j - 1], b = l[j];
    l[j - 1] = (a < b) ? a : b;
    l[j] = (a < b) ? b : a;
  }
}

__device__ __forceinline__ unsigned pack_key(float dist, int q) {
  return (__float_as_uint(dist) & 0xFFFFFC00u) | (unsigned)q;
}

// hi/lo bf16 split: |x - (hi+lo)| <= 2^-16 |x|
__device__ __forceinline__ void split_bf16(float x, short& hi, short& lo) {
  unsigned u = __float_as_uint(x);
  hi = (short)(u >> 16);
  float fh = __uint_as_float(u & 0xFFFF0000u);
  float r = x - fh;
  lo = (short)(__float_as_uint(r) >> 16);
}

// ---------------- kNN1 (D=3): register top-K, candidate-split ----------------
template <int S>
__global__ __launch_bounds__(256) void knn_topk3(const float* __restrict__ x,
                                                 unsigned* __restrict__ pk) {
  constexpr int CH = PP / S;
  int bx = blockIdx.x;
  int s = bx % S;
  int tile = (bx / S) % (PP / 256);
  int b = bx / (S * (PP / 256));
  int i = tile * 256 + threadIdx.x;
  const float* xb = x + (size_t)b * PP * 3;

  unsigned l[KK];
#pragma unroll
  for (int j = 0; j < KK; ++j) l[j] = 0xFFFFFFFFu;

  float xi0 = xb[(size_t)i * 3 + 0];
  float xi1 = xb[(size_t)i * 3 + 1];
  float xi2 = xb[(size_t)i * 3 + 2];
  for (int c = 0; c < CH; ++c) {
    int q = s * CH + c;  // block-uniform
    const float* cp = xb + (size_t)q * 3;
    float d0 = xi0 - cp[0], d1 = xi1 - cp[1], d2 = xi2 - cp[2];
    float dist = fmaf(d0, d0, fmaf(d1, d1, d2 * d2));
    topk_insert(l, pack_key(dist, q));
  }
  size_t base = ((size_t)b * PP + i) * S + s;
#pragma unroll
  for (int j = 0; j < KK; ++j) pk[base * KK + j] = l[j];
}

template <int S>
__global__ __launch_bounds__(256) void knn_merge(const unsigned* __restrict__ pk,
                                                 int* __restrict__ idx_out) {
  int p = blockIdx.x * 256 + threadIdx.x;
  const unsigned* g = pk + (size_t)p * S * KK;
  unsigned l[KK];
#pragma unroll
  for (int j = 0; j < KK; ++j) l[j] = g[j];
  for (int s = 1; s < S; ++s) {
    const unsigned* gs = g + s * KK;
#pragma unroll
    for (int j = 0; j < KK; ++j) topk_insert(l, gs[j]);
  }
#pragma unroll
  for (int j = 0; j < KK; ++j) idx_out[(size_t)p * KK + j] = (int)(l[j] & 1023u);
}

// ---------------- EdgeConv1 precompute ----------------
__global__ __launch_bounds__(256) void precompute1(const float* __restrict__ pos,
                                                   const float* __restrict__ W1,
                                                   const float* __restrict__ b1,
                                                   float* __restrict__ u1,
                                                   float* __restrict__ v1) {
  int gid = blockIdx.x * 256 + threadIdx.x;  // over N*64
  int i = gid >> 6, c = gid & 63;
  float p0 = pos[(size_t)i * 3 + 0], p1 = pos[(size_t)i * 3 + 1], p2 = pos[(size_t)i * 3 + 2];
  float a0 = W1[0 * 64 + c], a1 = W1[1 * 64 + c], a2 = W1[2 * 64 + c];
  float g0 = W1[3 * 64 + c], g1 = W1[4 * 64 + c], g2 = W1[5 * 64 + c];
  float v = fmaf(p0, g0, fmaf(p1, g1, p2 * g2));
  float u = b1[c];
  u = fmaf(p0, a0 - g0, u);
  u = fmaf(p1, a1 - g1, u);
  u = fmaf(p2, a2 - g2, u);
  u1[gid] = u;
  v1[gid] = v;
}

// ---------------- EdgeConv1 via MFMA (bf16 hi/lo x3 split) ----------------
// Block: 8 points -> 160 edge rows. A = relu-BN edge features (built in regs),
// B = W2 fragments, C (160x64) staged in padded LDS for per-point max over K.
__global__ __launch_bounds__(256) void edge_conv1_mfma(
    const float* __restrict__ u1, const float* __restrict__ v1,
    const int* __restrict__ idx, const float* __restrict__ W2,
    const float* __restrict__ scale, const float* __restrict__ bias,
    const float* __restrict__ b2, float* __restrict__ x1,
    short* __restrict__ x1h, short* __restrict__ x1l,
    float* __restrict__ sqn) {
  __shared__ float Cs[160 * 68];  // row pad 64->68: conflict-free col access
  __shared__ int jt[160];
  __shared__ float xs[512];
  int tid = threadIdx.x;
  int p0 = blockIdx.x * 8;  // global point base (8 | 1024: no cloud straddle)
  int b = p0 >> 10;
  if (tid < 160) {
    int e = tid;
    int i = p0 + e / 20;
    jt[e] = (b << 10) + idx[(size_t)i * KK + e % 20];
  }
  int w = tid >> 6, l = tid & 63, quad = l >> 4, lm = l & 15;
  int kq = quad * 8;
  // per-quad scale/bias (k = ks*32 + quad*8 + jj)
  float4 s00 = *(const float4*)(scale + kq);
  float4 s01 = *(const float4*)(scale + kq + 4);
  float4 s10 = *(const float4*)(scale + 32 + kq);
  float4 s11 = *(const float4*)(scale + 32 + kq + 4);
  float4 c00 = *(const float4*)(bias + kq);
  float4 c01 = *(const float4*)(bias + kq + 4);
  float4 c10 = *(const float4*)(bias + 32 + kq);
  float4 c11 = *(const float4*)(bias + 32 + kq + 4);
  // B fragments: B[k][n], lane holds n = lm, k = ks*32 + quad*8 + jj
  bf16x8 Bh[4][2], Bl[4][2];
#pragma unroll
  for (int nt = 0; nt < 4; ++nt) {
#pragma unroll
    for (int ks = 0; ks < 2; ++ks) {
#pragma unroll
      for (int jj = 0; jj < 8; ++jj) {
        float wv = W2[(size_t)(ks * 32 + kq + jj) * 64 + nt * 16 + lm];
        short hi, lo;
        split_bf16(wv, hi, lo);
        Bh[nt][ks][jj] = hi;
        Bl[nt][ks][jj] = lo;
      }
    }
  }
  __syncthreads();

  for (int s = w; s < 10; s += 4) {
    f32x4 acc[4];
#pragma unroll
    for (int nt = 0; nt < 4; ++nt) acc[nt] = (f32x4){0.f, 0.f, 0.f, 0.f};
    int e = s * 16 + lm;  // edge row (A m-index = lm)
    int p = e / 20;
    int jrow = jt[e];
    const float* urow = u1 + (size_t)(p0 + p) * 64;
    const float* vrow = v1 + (size_t)jrow * 64;
#pragma unroll
    for (int ks = 0; ks < 2; ++ks) {
      int koff = ks * 32 + kq;
      float4 va = *(const float4*)(vrow + koff);
      float4 vb = *(const float4*)(vrow + koff + 4);
      float4 ua = *(const float4*)(urow + koff);
      float4 ub = *(const float4*)(urow + koff + 4);
      float4 sA = ks ? s10 : s00, sB = ks ? s11 : s01;
      float4 cA = ks ? c10 : c00, cB = ks ? c11 : c01;
      float hv[8];
      hv[0] = fmaxf(fmaf(ua.x + va.x, sA.x, cA.x), 0.f);
      hv[1] = fmaxf(fmaf(ua.y + va.y, sA.y, cA.y), 0.f);
      hv[2] = fmaxf(fmaf(ua.z + va.z, sA.z, cA.z), 0.f);
      hv[3] = fmaxf(fmaf(ua.w + va.w, sA.w, cA.w), 0.f);
      hv[4] = fmaxf(fmaf(ub.x + vb.x, sB.x, cB.x), 0.f);
      hv[5] = fmaxf(fmaf(ub.y + vb.y, sB.y, cB.y), 0.f);
      hv[6] = fmaxf(fmaf(ub.z + vb.z, sB.z, cB.z), 0.f);
      hv[7] = fmaxf(fmaf(ub.w + vb.w, sB.w, cB.w), 0.f);
      bf16x8 Ah, Al;
#pragma unroll
      for (int jj = 0; jj < 8; ++jj) {
        short hi, lo;
        split_bf16(hv[jj], hi, lo);
        Ah[jj] = hi;
        Al[jj] = lo;
      }
#pragma unroll
      for (int nt = 0; nt < 4; ++nt) {
        acc[nt] = __builtin_amdgcn_mfma_f32_16x16x32_bf16(Ah, Bh[nt][ks], acc[nt], 0, 0, 0);
        acc[nt] = __builtin_amdgcn_mfma_f32_16x16x32_bf16(Al, Bh[nt][ks], acc[nt], 0, 0, 0);
        acc[nt] = __builtin_amdgcn_mfma_f32_16x16x32_bf16(Ah, Bl[nt][ks], acc[nt], 0, 0, 0);
      }
    }
    // C layout: row = quad*4 + r, col = lm (+16*nt)
#pragma unroll
    for (int nt = 0; nt < 4; ++nt) {
#pragma unroll
      for (int r = 0; r < 4; ++r) {
        Cs[(size_t)(s * 16 + quad * 4 + r) * 68 + nt * 16 + lm] = acc[nt][r];
      }
    }
  }
  __syncthreads();
  for (int o = tid; o < 512; o += 256) {
    int p = o >> 6, c = o & 63;
    float m = -__builtin_inff();
    for (int k = 0; k < KK; ++k) m = fmaxf(m, Cs[(size_t)(p * 20 + k) * 68 + c]);
    m += b2[c];
    size_t gi = (size_t)(p0 + p) * 64 + c;
    x1[gi] = m;
    short hi, lo;
    split_bf16(m, hi, lo);
    x1h[gi] = hi;
    x1l[gi] = lo;
    xs[o] = m;
  }
  __syncthreads();
  if (tid < 8) {
    float ss = 0.f;
    for (int c = 0; c < 64; ++c) {
      float v = xs[tid * 64 + c];
      ss = fmaf(v, v, ss);
    }
    sqn[p0 + tid] = ss;
  }
}

// ---------------- kNN2 via MFMA: n = point (lane-fixed), m = candidate ----------------
// Block: 4 waves x 16 points = 64 points, candidate half s. Each lane owns one
// point's distances for candidates m = m0 + quad*4 + r -> register top-K.
__global__ __launch_bounds__(256) void knn2_mfma(const short* __restrict__ x1h,
                                                 const short* __restrict__ x1l,
                                                 const float* __restrict__ sqn,
                                                 unsigned* __restrict__ pk) {
  __shared__ float sqs[1024];
  int bx = blockIdx.x;
  int s = bx & 1;
  int pb = bx >> 1;
  int p0 = pb * 64;  // global point base
  int b = p0 >> 10;
  int tid = threadIdx.x;
  for (int t = tid; t < 1024; t += 256) sqs[t] = sqn[(size_t)b * PP + t];
  int w = tid >> 6, l = tid & 63, quad = l >> 4, lm = l & 15;
  size_t gi = (size_t)p0 + w * 16 + lm;  // this lane's point (global)
  bf16x8 Bh[2], Bl[2];
#pragma unroll
  for (int ks = 0; ks < 2; ++ks) {
    Bh[ks] = *(const bf16x8*)(x1h + gi * 64 + ks * 32 + quad * 8);
    Bl[ks] = *(const bf16x8*)(x1l + gi * 64 + ks * 32 + quad * 8);
  }
  float sqi = sqn[gi];
  __syncthreads();
  unsigned list[KK];
#pragma unroll
  for (int j = 0; j < KK; ++j) list[j] = 0xFFFFFFFFu;
  for (int m0 = s * 512; m0 < s * 512 + 512; m0 += 16) {
    size_t ga = (size_t)b * PP + m0 + lm;  // A m-index = lm
    f32x4 acc = (f32x4){0.f, 0.f, 0.f, 0.f};
#pragma unroll
    for (int ks = 0; ks < 2; ++ks) {
      bf16x8 Ah = *(const bf16x8*)(x1h + ga * 64 + ks * 32 + quad * 8);
      bf16x8 Al = *(const bf16x8*)(x1l + ga * 64 + ks * 32 + quad * 8);
      acc = __builtin_amdgcn_mfma_f32_16x16x32_bf16(Ah, Bh[ks], acc, 0, 0, 0);
      acc = __builtin_amdgcn_mfma_f32_16x16x32_bf16(Al, Bh[ks], acc, 0, 0, 0);
      acc = __builtin_amdgcn_mfma_f32_16x16x32_bf16(Ah, Bl[ks], acc, 0, 0, 0);
    }
#pragma unroll
    for (int r = 0; r < 4; ++r) {
      int q = m0 + quad * 4 + r;  // C row = quad*4 + r
      float dist = fmaxf(0.f, fmaf(-2.f, acc[r], sqi + sqs[q]));
      topk_insert(list, pack_key(dist, q));
    }
  }
  unsigned sub = s * 4 + quad;
  unsigned* dst = pk + ((size_t)gi * 8 + sub) * KK;
#pragma unroll
  for (int j = 0; j < KK; ++j) dst[j] = list[j];
}

// ---------------- EdgeConv2 (linear -> u/v split) ----------------
__global__ __launch_bounds__(256) void precompute2(const float* __restrict__ x1,
                                                   const float* __restrict__ W,
                                                   const float* __restrict__ bb,
                                                   float* __restrict__ u2,
                                                   float* __restrict__ v2) {
  int gid = blockIdx.x * 256 + threadIdx.x;  // over (N/4)*128
  int c = gid & 127;
  int i0 = (gid >> 7) * 4;
  const float* a = x1 + (size_t)i0 * 64;
  float u0, u1r, u2r, u3, v0, v1r, v2r, v3;
  u0 = u1r = u2r = u3 = bb[c];
  v0 = v1r = v2r = v3 = 0.f;
  for (int t = 0; t < 64; ++t) {
    float wa = W[t * 128 + c];
    float wb = W[(64 + t) * 128 + c];
    float wd = wa - wb;
    float e0 = a[t], e1 = a[64 + t], e2 = a[128 + t], e3 = a[192 + t];
    u0 = fmaf(e0, wd, u0); v0 = fmaf(e0, wb, v0);
    u1r = fmaf(e1, wd, u1r); v1r = fmaf(e1, wb, v1r);
    u2r = fmaf(e2, wd, u2r); v2r = fmaf(e2, wb, v2r);
    u3 = fmaf(e3, wd, u3); v3 = fmaf(e3, wb, v3);
  }
  u2[(size_t)i0 * 128 + c] = u0;
  u2[(size_t)(i0 + 1) * 128 + c] = u1r;
  u2[(size_t)(i0 + 2) * 128 + c] = u2r;
  u2[(size_t)(i0 + 3) * 128 + c] = u3;
  v2[(size_t)i0 * 128 + c] = v0;
  v2[(size_t)(i0 + 1) * 128 + c] = v1r;
  v2[(size_t)(i0 + 2) * 128 + c] = v2r;
  v2[(size_t)(i0 + 3) * 128 + c] = v3;
}

__global__ __launch_bounds__(256) void gathermax2(const float* __restrict__ u2,
                                                  const float* __restrict__ v2,
                                                  const int* __restrict__ idx,
                                                  float* __restrict__ x2) {
  int gid = blockIdx.x * 256 + threadIdx.x;  // over N*128
  int i = gid >> 7, c = gid & 127;
  int b = i >> 10;
  const int* myidx = idx + (size_t)i * KK;
  float m = -__builtin_inff();
  for (int k = 0; k < KK; ++k) {
    int j = (b << 10) + myidx[k];
    m = fmaxf(m, v2[(size_t)j * 128 + c]);
  }
  x2[gid] = u2[gid] + m;
}

// ---------------- final linear + segment max ----------------
__global__ __launch_bounds__(256) void lin_kernel(const float* __restrict__ x1,
                                                  const float* __restrict__ x2,
                                                  const float* __restrict__ LW,
                                                  const float* __restrict__ lb,
                                                  float* __restrict__ h) {
  int gid = blockIdx.x * 256 + threadIdx.x;  // over (N/4)*128
  int c = gid & 127;
  int i0 = (gid >> 7) * 4;
  float o0 = lb[c], o1 = o0, o2 = o0, o3 = o0;
  const float* a = x1 + (size_t)i0 * 64;
  for (int t = 0; t < 64; ++t) {
    float w = LW[t * 128 + c];
    o0 = fmaf(a[t], w, o0);
    o1 = fmaf(a[64 + t], w, o1);
    o2 = fmaf(a[128 + t], w, o2);
    o3 = fmaf(a[192 + t], w, o3);
  }
  const float* g = x2 + (size_t)i0 * 128;
  for (int t = 0; t < 128; ++t) {
    float w = LW[(64 + t) * 128 + c];
    o0 = fmaf(g[t], w, o0);
    o1 = fmaf(g[128 + t], w, o1);
    o2 = fmaf(g[256 + t], w, o2);
    o3 = fmaf(g[384 + t], w, o3);
  }
  h[(size_t)i0 * 128 + c] = o0;
  h[(size_t)(i0 + 1) * 128 + c] = o1;
  h[(size_t)(i0 + 2) * 128 + c] = o2;
  h[(size_t)(i0 + 3) * 128 + c] = o3;
}

__global__ __launch_bounds__(128) void segmax_a(const float* __restrict__ h,
                                                float* __restrict__ part) {
  int b = blockIdx.x >> 3, chunk = blockIdx.x & 7;
  int c = threadIdx.x;
  float m = -__builtin_inff();
  for (int p = 0; p < 128; ++p) {
    size_t i = (size_t)b * PP + chunk * 128 + p;
    m = fmaxf(m, h[i * 128 + c]);
  }
  part[(size_t)blockIdx.x * 128 + c] = m;
}

__global__ __launch_bounds__(128) void segmax_b(const float* __restrict__ part,
                                                float* __restrict__ out) {
  int b = blockIdx.x;
  int c = threadIdx.x;
  float m = -__builtin_inff();
  for (int k = 0; k < 8; ++k) m = fmaxf(m, part[((size_t)b * 8 + k) * 128 + c]);
  out[(size_t)b * 128 + c] = m;
}

// ---------------- launch ----------------
extern "C" void kernel_launch(void* const* d_in, const int* in_sizes, int n_in,
                              void* d_out, int out_size, void* d_ws, size_t ws_size,
                              hipStream_t stream) {
  const float* pos = (const float*)d_in[0];
  const float* W1 = (const float*)d_in[2];
  const float* b1 = (const float*)d_in[3];
  const float* bn_s = (const float*)d_in[4];
  const float* bn_b = (const float*)d_in[5];
  const float* W2 = (const float*)d_in[6];
  const float* b2 = (const float*)d_in[7];
  const float* cW = (const float*)d_in[8];
  const float* cb = (const float*)d_in[9];
  const float* LW = (const float*)d_in[10];
  const float* lb = (const float*)d_in[11];
  float* out = (float*)d_out;

  char* ws = (char*)d_ws;
  float* x1 = (float*)(ws + OFF_X1);
  int* idx = (int*)(ws + OFF_IDX);
  float* u1 = (float*)(ws + OFF_U);
  float* v1 = (float*)(ws + OFF_V);
  short* x1h = (short*)(ws + OFF_U + (size_t)NPTS * 64 * 4);  // U 2nd half
  short* x1l = (short*)(ws + OFF_V + (size_t)NPTS * 64 * 4);  // V 2nd half
  float* u2 = u1;
  float* v2 = v1;
  float* x2 = (float*)(ws + OFF_X2);
  float* hbuf = (float*)(ws + OFF_H);
  float* part = (float*)(ws + OFF_PART);
  float* sqn = (float*)(ws + OFF_SQN);
  unsigned* pk = (unsigned*)(ws + OFF_X2);  // spans x2 + start of h; disjoint lifetime

  // 1. kNN on pos
  knn_topk3<4><<<NB * 4 * 4, 256, 0, stream>>>(pos, pk);
  knn_merge<4><<<NPTS / 256, 256, 0, stream>>>(pk, idx);
  // 2. u1/v1
  precompute1<<<NPTS * 64 / 256, 256, 0, stream>>>(pos, W1, b1, u1, v1);
  // 3. EdgeConv1 (MFMA) -> x1 fp32 + bf16 hi/lo + sqn
  edge_conv1_mfma<<<NPTS / 8, 256, 0, stream>>>(u1, v1, idx, W2, bn_s, bn_b, b2,
                                                x1, x1h, x1l, sqn);
  // 4. kNN on x1 (MFMA distances, 2-way cand split x 4 quad sublists)
  knn2_mfma<<<NPTS / 64 * 2, 256, 0, stream>>>(x1h, x1l, sqn, pk);
  knn_merge<8><<<NPTS / 256, 256, 0, stream>>>(pk, idx);
  // 5. u2/v2
  precompute2<<<(NPTS / 4) * 128 / 256, 256, 0, stream>>>(x1, cW, cb, u2, v2);
  // 6. gather + max -> x2
  gathermax2<<<NPTS * 128 / 256, 256, 0, stream>>>(u2, v2, idx, x2);
  // 7. final linear -> h
  lin_kernel<<<(NPTS / 4) * 128 / 256, 256, 0, stream>>>(x1, x2, LW, lb, hbuf);
  // 8. segment max -> out
  segmax_a<<<NB * 8, 128, 0, stream>>>(hbuf, part);
  segmax_b<<<NB, 128, 0, stream>>>(part, out);
}

// Round 4
// 376.954 us; speedup vs baseline: 5.8592x; 1.2942x over previous
//
#include <hip/hip_runtime.h>
#include <math.h>

#define NPTS 32768
#define NB 32
#define PP 1024
#define KK 20

using bf16x8 = __attribute__((ext_vector_type(8))) short;
using f32x4 = __attribute__((ext_vector_type(4))) float;

// ---------------- workspace layout ----------------
// X1 region now holds x1h/x1l bf16 (x1 fp32 no longer exists — every consumer
// uses the hi/lo split). They must survive until lin_mfma (step 7): nothing
// overwrites the X1 region. pk aliases X2+H-start, dead before x2h/x2l/h.
constexpr size_t OFF_X1 = 0;                                  // x1h[N,64]bf16 + x1l[N,64]bf16
constexpr size_t OFF_IDX = OFF_X1 + (size_t)NPTS * 64 * 4;    // [N,20] i32
constexpr size_t OFF_U = OFF_IDX + (size_t)NPTS * KK * 4;     // u2 [N,128] f32
constexpr size_t OFF_V = OFF_U + (size_t)NPTS * 128 * 4;      // v2 [N,128] f32
constexpr size_t OFF_X2 = OFF_V + (size_t)NPTS * 128 * 4;     // x2h + x2l bf16 [N,128] each
constexpr size_t OFF_H = OFF_X2 + (size_t)NPTS * 128 * 4;     // h [N,128] f32
constexpr size_t OFF_PART = OFF_H + (size_t)NPTS * 128 * 4;   // 32*8*128 f32
constexpr size_t OFF_SQN = OFF_PART + (size_t)32 * 8 * 128 * 4;  // [N] f32

// ---------------- branch-free register top-K ----------------
__device__ __forceinline__ void topk_insert(unsigned (&l)[KK], unsigned key) {
  l[KK - 1] = (key < l[KK - 1]) ? key : l[KK - 1];
#pragma unroll
  for (int j = KK - 1; j >= 1; --j) {
    unsigned a = l[j - 1], b = l[j];
    l[j - 1] = (a < b) ? a : b;
    l[j] = (a < b) ? b : a;
  }
}

__device__ __forceinline__ unsigned pack_key(float dist, int q) {
  return (__float_as_uint(dist) & 0xFFFFFC00u) | (unsigned)q;
}

// hi/lo bf16 split: |x - (hi+lo)| <= 2^-16 |x|
__device__ __forceinline__ void split_bf16(float x, short& hi, short& lo) {
  unsigned u = __float_as_uint(x);
  hi = (short)(u >> 16);
  float fh = __uint_as_float(u & 0xFFFF0000u);
  float r = x - fh;
  lo = (short)(__float_as_uint(r) >> 16);
}

// ---------------- kNN1 (D=3) ----------------
template <int S>
__global__ __launch_bounds__(256) void knn_topk3(const float* __restrict__ x,
                                                 unsigned* __restrict__ pk) {
  constexpr int CH = PP / S;
  int bx = blockIdx.x;
  int s = bx % S;
  int tile = (bx / S) % (PP / 256);
  int b = bx / (S * (PP / 256));
  int i = tile * 256 + threadIdx.x;
  const float* xb = x + (size_t)b * PP * 3;

  unsigned l[KK];
#pragma unroll
  for (int j = 0; j < KK; ++j) l[j] = 0xFFFFFFFFu;

  float xi0 = xb[(size_t)i * 3 + 0];
  float xi1 = xb[(size_t)i * 3 + 1];
  float xi2 = xb[(size_t)i * 3 + 2];
  for (int c = 0; c < CH; ++c) {
    int q = s * CH + c;  // block-uniform
    const float* cp = xb + (size_t)q * 3;
    float d0 = xi0 - cp[0], d1 = xi1 - cp[1], d2 = xi2 - cp[2];
    float dist = fmaf(d0, d0, fmaf(d1, d1, d2 * d2));
    topk_insert(l, pack_key(dist, q));
  }
  size_t base = ((size_t)b * PP + i) * S + s;
#pragma unroll
  for (int j = 0; j < KK; ++j) pk[base * KK + j] = l[j];
}

template <int S>
__global__ __launch_bounds__(256) void knn_merge(const unsigned* __restrict__ pk,
                                                 int* __restrict__ idx_out) {
  int p = blockIdx.x * 256 + threadIdx.x;
  const unsigned* g = pk + (size_t)p * S * KK;
  unsigned l[KK];
#pragma unroll
  for (int j = 0; j < KK; ++j) l[j] = g[j];
  for (int s = 1; s < S; ++s) {
    const unsigned* gs = g + s * KK;
#pragma unroll
    for (int j = 0; j < KK; ++j) topk_insert(l, gs[j]);
  }
#pragma unroll
  for (int j = 0; j < KK; ++j) idx_out[(size_t)p * KK + j] = (int)(l[j] & 1023u);
}

// ---------------- EdgeConv1 precompute ----------------
__global__ __launch_bounds__(256) void precompute1(const float* __restrict__ pos,
                                                   const float* __restrict__ W1,
                                                   const float* __restrict__ b1,
                                                   float* __restrict__ u1,
                                                   float* __restrict__ v1) {
  int gid = blockIdx.x * 256 + threadIdx.x;  // over N*64
  int i = gid >> 6, c = gid & 63;
  float p0 = pos[(size_t)i * 3 + 0], p1 = pos[(size_t)i * 3 + 1], p2 = pos[(size_t)i * 3 + 2];
  float a0 = W1[0 * 64 + c], a1 = W1[1 * 64 + c], a2 = W1[2 * 64 + c];
  float g0 = W1[3 * 64 + c], g1 = W1[4 * 64 + c], g2 = W1[5 * 64 + c];
  float v = fmaf(p0, g0, fmaf(p1, g1, p2 * g2));
  float u = b1[c];
  u = fmaf(p0, a0 - g0, u);
  u = fmaf(p1, a1 - g1, u);
  u = fmaf(p2, a2 - g2, u);
  u1[gid] = u;
  v1[gid] = v;
}

// ---------------- EdgeConv1 via MFMA ----------------
__global__ __launch_bounds__(256) void edge_conv1_mfma(
    const float* __restrict__ u1, const float* __restrict__ v1,
    const int* __restrict__ idx, const float* __restrict__ W2,
    const float* __restrict__ scale, const float* __restrict__ bias,
    const float* __restrict__ b2,
    short* __restrict__ x1h, short* __restrict__ x1l,
    float* __restrict__ sqn) {
  __shared__ float Cs[160 * 68];
  __shared__ int jt[160];
  __shared__ float xs[512];
  int tid = threadIdx.x;
  int p0 = blockIdx.x * 8;
  int b = p0 >> 10;
  if (tid < 160) {
    int e = tid;
    int i = p0 + e / 20;
    jt[e] = (b << 10) + idx[(size_t)i * KK + e % 20];
  }
  int w = tid >> 6, l = tid & 63, quad = l >> 4, lm = l & 15;
  int kq = quad * 8;
  float4 s00 = *(const float4*)(scale + kq);
  float4 s01 = *(const float4*)(scale + kq + 4);
  float4 s10 = *(const float4*)(scale + 32 + kq);
  float4 s11 = *(const float4*)(scale + 32 + kq + 4);
  float4 c00 = *(const float4*)(bias + kq);
  float4 c01 = *(const float4*)(bias + kq + 4);
  float4 c10 = *(const float4*)(bias + 32 + kq);
  float4 c11 = *(const float4*)(bias + 32 + kq + 4);
  bf16x8 Bh[4][2], Bl[4][2];
#pragma unroll
  for (int nt = 0; nt < 4; ++nt) {
#pragma unroll
    for (int ks = 0; ks < 2; ++ks) {
#pragma unroll
      for (int jj = 0; jj < 8; ++jj) {
        float wv = W2[(size_t)(ks * 32 + kq + jj) * 64 + nt * 16 + lm];
        short hi, lo;
        split_bf16(wv, hi, lo);
        Bh[nt][ks][jj] = hi;
        Bl[nt][ks][jj] = lo;
      }
    }
  }
  __syncthreads();

  for (int s = w; s < 10; s += 4) {
    f32x4 acc[4];
#pragma unroll
    for (int nt = 0; nt < 4; ++nt) acc[nt] = (f32x4){0.f, 0.f, 0.f, 0.f};
    int e = s * 16 + lm;
    int p = e / 20;
    int jrow = jt[e];
    const float* urow = u1 + (size_t)(p0 + p) * 64;
    const float* vrow = v1 + (size_t)jrow * 64;
#pragma unroll
    for (int ks = 0; ks < 2; ++ks) {
      int koff = ks * 32 + kq;
      float4 va = *(const float4*)(vrow + koff);
      float4 vb = *(const float4*)(vrow + koff + 4);
      float4 ua = *(const float4*)(urow + koff);
      float4 ub = *(const float4*)(urow + koff + 4);
      float4 sA = ks ? s10 : s00, sB = ks ? s11 : s01;
      float4 cA = ks ? c10 : c00, cB = ks ? c11 : c01;
      float hv[8];
      hv[0] = fmaxf(fmaf(ua.x + va.x, sA.x, cA.x), 0.f);
      hv[1] = fmaxf(fmaf(ua.y + va.y, sA.y, cA.y), 0.f);
      hv[2] = fmaxf(fmaf(ua.z + va.z, sA.z, cA.z), 0.f);
      hv[3] = fmaxf(fmaf(ua.w + va.w, sA.w, cA.w), 0.f);
      hv[4] = fmaxf(fmaf(ub.x + vb.x, sB.x, cB.x), 0.f);
      hv[5] = fmaxf(fmaf(ub.y + vb.y, sB.y, cB.y), 0.f);
      hv[6] = fmaxf(fmaf(ub.z + vb.z, sB.z, cB.z), 0.f);
      hv[7] = fmaxf(fmaf(ub.w + vb.w, sB.w, cB.w), 0.f);
      bf16x8 Ah, Al;
#pragma unroll
      for (int jj = 0; jj < 8; ++jj) {
        short hi, lo;
        split_bf16(hv[jj], hi, lo);
        Ah[jj] = hi;
        Al[jj] = lo;
      }
#pragma unroll
      for (int nt = 0; nt < 4; ++nt) {
        acc[nt] = __builtin_amdgcn_mfma_f32_16x16x32_bf16(Ah, Bh[nt][ks], acc[nt], 0, 0, 0);
        acc[nt] = __builtin_amdgcn_mfma_f32_16x16x32_bf16(Al, Bh[nt][ks], acc[nt], 0, 0, 0);
        acc[nt] = __builtin_amdgcn_mfma_f32_16x16x32_bf16(Ah, Bl[nt][ks], acc[nt], 0, 0, 0);
      }
    }
#pragma unroll
    for (int nt = 0; nt < 4; ++nt) {
#pragma unroll
      for (int r = 0; r < 4; ++r) {
        Cs[(size_t)(s * 16 + quad * 4 + r) * 68 + nt * 16 + lm] = acc[nt][r];
      }
    }
  }
  __syncthreads();
  for (int o = tid; o < 512; o += 256) {
    int p = o >> 6, c = o & 63;
    float m = -__builtin_inff();
    for (int k = 0; k < KK; ++k) m = fmaxf(m, Cs[(size_t)(p * 20 + k) * 68 + c]);
    m += b2[c];
    size_t gi = (size_t)(p0 + p) * 64 + c;
    short hi, lo;
    split_bf16(m, hi, lo);
    x1h[gi] = hi;
    x1l[gi] = lo;
    xs[o] = m;
  }
  __syncthreads();
  if (tid < 8) {
    float ss = 0.f;
    for (int c = 0; c < 64; ++c) {
      float v = xs[tid * 64 + c];
      ss = fmaf(v, v, ss);
    }
    sqn[p0 + tid] = ss;
  }
}

// ---------------- kNN2 via MFMA ----------------
__global__ __launch_bounds__(256) void knn2_mfma(const short* __restrict__ x1h,
                                                 const short* __restrict__ x1l,
                                                 const float* __restrict__ sqn,
                                                 unsigned* __restrict__ pk) {
  __shared__ float sqs[1024];
  int bx = blockIdx.x;
  int s = bx & 1;
  int pb = bx >> 1;
  int p0 = pb * 64;
  int b = p0 >> 10;
  int tid = threadIdx.x;
  for (int t = tid; t < 1024; t += 256) sqs[t] = sqn[(size_t)b * PP + t];
  int w = tid >> 6, l = tid & 63, quad = l >> 4, lm = l & 15;
  size_t gi = (size_t)p0 + w * 16 + lm;
  bf16x8 Bh[2], Bl[2];
#pragma unroll
  for (int ks = 0; ks < 2; ++ks) {
    Bh[ks] = *(const bf16x8*)(x1h + gi * 64 + ks * 32 + quad * 8);
    Bl[ks] = *(const bf16x8*)(x1l + gi * 64 + ks * 32 + quad * 8);
  }
  float sqi = sqn[gi];
  __syncthreads();
  unsigned list[KK];
#pragma unroll
  for (int j = 0; j < KK; ++j) list[j] = 0xFFFFFFFFu;
  for (int m0 = s * 512; m0 < s * 512 + 512; m0 += 16) {
    size_t ga = (size_t)b * PP + m0 + lm;
    f32x4 acc = (f32x4){0.f, 0.f, 0.f, 0.f};
#pragma unroll
    for (int ks = 0; ks < 2; ++ks) {
      bf16x8 Ah = *(const bf16x8*)(x1h + ga * 64 + ks * 32 + quad * 8);
      bf16x8 Al = *(const bf16x8*)(x1l + ga * 64 + ks * 32 + quad * 8);
      acc = __builtin_amdgcn_mfma_f32_16x16x32_bf16(Ah, Bh[ks], acc, 0, 0, 0);
      acc = __builtin_amdgcn_mfma_f32_16x16x32_bf16(Al, Bh[ks], acc, 0, 0, 0);
      acc = __builtin_amdgcn_mfma_f32_16x16x32_bf16(Ah, Bl[ks], acc, 0, 0, 0);
    }
#pragma unroll
    for (int r = 0; r < 4; ++r) {
      int q = m0 + quad * 4 + r;
      float dist = fmaxf(0.f, fmaf(-2.f, acc[r], sqi + sqs[q]));
      topk_insert(list, pack_key(dist, q));
    }
  }
  unsigned sub = s * 4 + quad;
  unsigned* dst = pk + ((size_t)gi * 8 + sub) * KK;
#pragma unroll
  for (int j = 0; j < KK; ++j) dst[j] = list[j];
}

// ---------------- EdgeConv2 precompute via MFMA ----------------
// u2 = x1@(Wtop-Wbot)+cb (nh=0), v2 = x1@Wbot (nh=1). B built in LDS from cW.
__global__ __launch_bounds__(256) void pre2_mfma(const short* __restrict__ x1h,
                                                 const short* __restrict__ x1l,
                                                 const float* __restrict__ cW,
                                                 const float* __restrict__ cb,
                                                 float* __restrict__ u2,
                                                 float* __restrict__ v2) {
  constexpr int BS = 72;  // LDS row stride (shorts): 2-way-only bank aliasing
  __shared__ short Bh[128 * BS];
  __shared__ short Bl[128 * BS];
  int tid = threadIdx.x;
  int nh = blockIdx.x & 1;
  int p0 = (blockIdx.x >> 1) * 64;
  for (int t = tid; t < 64 * 128; t += 256) {
    int k = t >> 7, n = t & 127;
    float wb_ = cW[(size_t)(64 + k) * 128 + n];
    float wv = nh ? wb_ : (cW[(size_t)k * 128 + n] - wb_);
    short hi, lo;
    split_bf16(wv, hi, lo);
    Bh[n * BS + k] = hi;
    Bl[n * BS + k] = lo;
  }
  __syncthreads();
  int w = tid >> 6, l = tid & 63, quad = l >> 4, lm = l & 15;
  int row = p0 + w * 16 + lm;
  f32x4 acc[8];
#pragma unroll
  for (int nt = 0; nt < 8; ++nt) acc[nt] = (f32x4){0.f, 0.f, 0.f, 0.f};
#pragma unroll
  for (int ks = 0; ks < 2; ++ks) {
    int kb = ks * 32 + quad * 8;
    bf16x8 Ah = *(const bf16x8*)(x1h + (size_t)row * 64 + kb);
    bf16x8 Al = *(const bf16x8*)(x1l + (size_t)row * 64 + kb);
#pragma unroll
    for (int nt = 0; nt < 8; ++nt) {
      bf16x8 Wh = *(const bf16x8*)(Bh + (nt * 16 + lm) * BS + kb);
      bf16x8 Wl = *(const bf16x8*)(Bl + (nt * 16 + lm) * BS + kb);
      acc[nt] = __builtin_amdgcn_mfma_f32_16x16x32_bf16(Ah, Wh, acc[nt], 0, 0, 0);
      acc[nt] = __builtin_amdgcn_mfma_f32_16x16x32_bf16(Al, Wh, acc[nt], 0, 0, 0);
      acc[nt] = __builtin_amdgcn_mfma_f32_16x16x32_bf16(Ah, Wl, acc[nt], 0, 0, 0);
    }
  }
  float* out = nh ? v2 : u2;
  int prow = p0 + w * 16 + quad * 4;
#pragma unroll
  for (int nt = 0; nt < 8; ++nt) {
    int col = nt * 16 + lm;
    float bias = nh ? 0.f : cb[col];
#pragma unroll
    for (int r = 0; r < 4; ++r)
      out[(size_t)(prow + r) * 128 + col] = acc[nt][r] + bias;
  }
}

__global__ __launch_bounds__(256) void gathermax2(const float* __restrict__ u2,
                                                  const float* __restrict__ v2,
                                                  const int* __restrict__ idx,
                                                  short* __restrict__ x2h,
                                                  short* __restrict__ x2l) {
  int gid = blockIdx.x * 256 + threadIdx.x;  // over N*128
  int i = gid >> 7, c = gid & 127;
  int b = i >> 10;
  const int* myidx = idx + (size_t)i * KK;
  float m = -__builtin_inff();
  for (int k = 0; k < KK; ++k) {
    int j = (b << 10) + myidx[k];
    m = fmaxf(m, v2[(size_t)j * 128 + c]);
  }
  float x = u2[gid] + m;
  short hi, lo;
  split_bf16(x, hi, lo);
  x2h[gid] = hi;
  x2l[gid] = lo;
}

// ---------------- final linear via MFMA ----------------
__global__ __launch_bounds__(256) void lin_mfma(const short* __restrict__ x1h,
                                                const short* __restrict__ x1l,
                                                const short* __restrict__ x2h,
                                                const short* __restrict__ x2l,
                                                const float* __restrict__ LW,
                                                const float* __restrict__ lb,
                                                float* __restrict__ h) {
  constexpr int BS = 200;  // LDS row stride (shorts)
  __shared__ short Bh[64 * BS];
  __shared__ short Bl[64 * BS];
  int tid = threadIdx.x;
  int nh = blockIdx.x & 1;
  int p0 = (blockIdx.x >> 1) * 64;
  for (int t = tid; t < 192 * 64; t += 256) {
    int k = t >> 6, n = t & 63;
    float wv = LW[(size_t)k * 128 + nh * 64 + n];
    short hi, lo;
    split_bf16(wv, hi, lo);
    Bh[n * BS + k] = hi;
    Bl[n * BS + k] = lo;
  }
  __syncthreads();
  int w = tid >> 6, l = tid & 63, quad = l >> 4, lm = l & 15;
  int row = p0 + w * 16 + lm;  // A m = lm
  f32x4 acc[4];
#pragma unroll
  for (int nt = 0; nt < 4; ++nt) acc[nt] = (f32x4){0.f, 0.f, 0.f, 0.f};
#pragma unroll
  for (int ks = 0; ks < 6; ++ks) {
    int kb = ks * 32 + quad * 8;
    bf16x8 Ah, Al;
    if (ks < 2) {
      Ah = *(const bf16x8*)(x1h + (size_t)row * 64 + kb);
      Al = *(const bf16x8*)(x1l + (size_t)row * 64 + kb);
    } else {
      Ah = *(const bf16x8*)(x2h + (size_t)row * 128 + (kb - 64));
      Al = *(const bf16x8*)(x2l + (size_t)row * 128 + (kb - 64));
    }
#pragma unroll
    for (int nt = 0; nt < 4; ++nt) {
      bf16x8 Wh = *(const bf16x8*)(Bh + (nt * 16 + lm) * BS + kb);
      bf16x8 Wl = *(const bf16x8*)(Bl + (nt * 16 + lm) * BS + kb);
      acc[nt] = __builtin_amdgcn_mfma_f32_16x16x32_bf16(Ah, Wh, acc[nt], 0, 0, 0);
      acc[nt] = __builtin_amdgcn_mfma_f32_16x16x32_bf16(Al, Wh, acc[nt], 0, 0, 0);
      acc[nt] = __builtin_amdgcn_mfma_f32_16x16x32_bf16(Ah, Wl, acc[nt], 0, 0, 0);
    }
  }
  int prow = p0 + w * 16 + quad * 4;
#pragma unroll
  for (int nt = 0; nt < 4; ++nt) {
    int col = nh * 64 + nt * 16 + lm;
    float bias = lb[col];
#pragma unroll
    for (int r = 0; r < 4; ++r)
      h[(size_t)(prow + r) * 128 + col] = acc[nt][r] + bias;
  }
}

// ---------------- segment max ----------------
__global__ __launch_bounds__(128) void segmax_a(const float* __restrict__ h,
                                                float* __restrict__ part) {
  int b = blockIdx.x >> 3, chunk = blockIdx.x & 7;
  int c = threadIdx.x;
  float m = -__builtin_inff();
  for (int p = 0; p < 128; ++p) {
    size_t i = (size_t)b * PP + chunk * 128 + p;
    m = fmaxf(m, h[i * 128 + c]);
  }
  part[(size_t)blockIdx.x * 128 + c] = m;
}

__global__ __launch_bounds__(128) void segmax_b(const float* __restrict__ part,
                                                float* __restrict__ out) {
  int b = blockIdx.x;
  int c = threadIdx.x;
  float m = -__builtin_inff();
  for (int k = 0; k < 8; ++k) m = fmaxf(m, part[((size_t)b * 8 + k) * 128 + c]);
  out[(size_t)b * 128 + c] = m;
}

// ---------------- launch ----------------
extern "C" void kernel_launch(void* const* d_in, const int* in_sizes, int n_in,
                              void* d_out, int out_size, void* d_ws, size_t ws_size,
                              hipStream_t stream) {
  const float* pos = (const float*)d_in[0];
  const float* W1 = (const float*)d_in[2];
  const float* b1 = (const float*)d_in[3];
  const float* bn_s = (const float*)d_in[4];
  const float* bn_b = (const float*)d_in[5];
  const float* W2 = (const float*)d_in[6];
  const float* b2 = (const float*)d_in[7];
  const float* cW = (const float*)d_in[8];
  const float* cb = (const float*)d_in[9];
  const float* LW = (const float*)d_in[10];
  const float* lb = (const float*)d_in[11];
  float* out = (float*)d_out;

  char* ws = (char*)d_ws;
  short* x1h = (short*)(ws + OFF_X1);
  short* x1l = (short*)(ws + OFF_X1 + (size_t)NPTS * 64 * 2);
  int* idx = (int*)(ws + OFF_IDX);
  float* u1 = (float*)(ws + OFF_U);   // u1/v1 [N,64] dead after edge_conv1;
  float* v1 = (float*)(ws + OFF_V);   // regions reused as u2/v2 [N,128]
  float* u2 = (float*)(ws + OFF_U);
  float* v2 = (float*)(ws + OFF_V);
  short* x2h = (short*)(ws + OFF_X2);
  short* x2l = (short*)(ws + OFF_X2 + (size_t)NPTS * 128 * 2);
  float* hbuf = (float*)(ws + OFF_H);
  float* part = (float*)(ws + OFF_PART);
  float* sqn = (float*)(ws + OFF_SQN);
  unsigned* pk = (unsigned*)(ws + OFF_X2);  // spans x2..h-start; disjoint lifetime

  // 1. kNN on pos
  knn_topk3<4><<<NB * 4 * 4, 256, 0, stream>>>(pos, pk);
  knn_merge<4><<<NPTS / 256, 256, 0, stream>>>(pk, idx);
  // 2. u1/v1
  precompute1<<<NPTS * 64 / 256, 256, 0, stream>>>(pos, W1, b1, u1, v1);
  // 3. EdgeConv1 (MFMA) -> x1 bf16 hi/lo + sqn
  edge_conv1_mfma<<<NPTS / 8, 256, 0, stream>>>(u1, v1, idx, W2, bn_s, bn_b, b2,
                                                x1h, x1l, sqn);
  // 4. kNN on x1 (MFMA distances)
  knn2_mfma<<<NPTS / 64 * 2, 256, 0, stream>>>(x1h, x1l, sqn, pk);
  knn_merge<8><<<NPTS / 256, 256, 0, stream>>>(pk, idx);
  // 5. u2/v2 (MFMA)
  pre2_mfma<<<NPTS / 64 * 2, 256, 0, stream>>>(x1h, x1l, cW, cb, u2, v2);
  // 6. gather + max -> x2 bf16 hi/lo
  gathermax2<<<NPTS * 128 / 256, 256, 0, stream>>>(u2, v2, idx, x2h, x2l);
  // 7. final linear (MFMA) -> h
  lin_mfma<<<NPTS / 64 * 2, 256, 0, stream>>>(x1h, x1l, x2h, x2l, LW, lb, hbuf);
  // 8. segment max -> out
  segmax_a<<<NB * 8, 128, 0, stream>>>(hbuf, part);
  segmax_b<<<NB, 128, 0, stream>>>(part, out);
}